// Round 5
// baseline (552.612 us; speedup 1.0000x reference)
//
#include <hip/hip_runtime.h>
#include <math.h>

#define BGR 32
#define NPER0 1024
#define N0 (BGR * NPER0)
#define FDIM 128
#define EDG 524288
#define EPG (EDG / BGR)
#define K1 512
#define K2 256
#define K3 128
#define PGJ 8  // kept nodes per poolgather block

// ---------------------------------------------------------------------------
// Parallel CSR build: zero -> count (atomic, 1 thread/edge) -> per-graph scan
// -> scatter (atomic cursor, 1 thread/edge). Edge validity = (src[e] >= 0).
// ---------------------------------------------------------------------------
__global__ void zero_int(int* __restrict__ p, int n) {
    int i = blockIdx.x * 256 + threadIdx.x;
    if (i < n) p[i] = 0;
}

__global__ void count_kernel(const int* __restrict__ src, const int* __restrict__ dst,
                             int* __restrict__ cnt) {
    int e = blockIdx.x * 256 + threadIdx.x;
    int s = src[e];
    if (s >= 0) atomicAdd(&cnt[dst[e]], 1);
}

// Per-graph exclusive scan of cnt -> rowptr; writes dinv/rowcnt; zeroes cnt
// (reused as scatter cursor). 32 blocks x 256 threads over nper<=1024 elems.
__global__ void scan_kernel(int* __restrict__ cnt, int nper,
                            float* __restrict__ dinv,
                            int* __restrict__ rowptr, int* __restrict__ rowcnt) {
    __shared__ int scnt[NPER0];
    __shared__ int soff[NPER0];
    __shared__ int psum[256];
    const int g = blockIdx.x, t = threadIdx.x;
    const int gnb = g * nper, ebase = g * EPG;
    for (int i = t; i < nper; i += 256) scnt[i] = cnt[gnb + i];
    __syncthreads();
    const int S = nper >> 8;  // 4, 2, or 1
    const int b0 = t * S;
    int loc = 0;
    for (int q = 0; q < S; q++) loc += scnt[b0 + q];
    psum[t] = loc;
    __syncthreads();
    if (t == 0) {
        int run = 0;
        for (int i = 0; i < 256; i++) { int v = psum[i]; psum[i] = run; run += v; }
    }
    __syncthreads();
    int run = psum[t];
    for (int q = 0; q < S; q++) { soff[b0 + q] = run; run += scnt[b0 + q]; }
    __syncthreads();
    for (int i = t; i < nper; i += 256) {
        int c = scnt[i];
        dinv[gnb + i] = rsqrtf((float)c + 1.0f);
        rowptr[gnb + i] = ebase + soff[i];
        rowcnt[gnb + i] = c;
        cnt[gnb + i] = 0;  // cursor for scatter
    }
}

__global__ void scatter_kernel(const int* __restrict__ src, const int* __restrict__ dst,
                               const int* __restrict__ rowptr, int* __restrict__ cursor,
                               int* __restrict__ csr_src) {
    int e = blockIdx.x * 256 + threadIdx.x;
    int s = src[e];
    if (s >= 0) {
        int d = dst[e];
        int p = atomicAdd(&cursor[d], 1);
        csr_src[rowptr[d] + p] = s;
    }
}

// ---------------------------------------------------------------------------
// Per-head projection: h[i, h*32+e] = sum_d x[i, h*32+d] * W[h, d, e].
// Block = 128 threads (one output feature each), 32 nodes per block.
// ---------------------------------------------------------------------------
__global__ void proj_kernel(const float* __restrict__ x, const float* __restrict__ W,
                            float* __restrict__ hp) {
    __shared__ float sW[4096];
    __shared__ float sx[32][128];
    const int t = threadIdx.x;
    const int nb = blockIdx.x * 32;
    for (int i = t; i < 4096; i += 128) sW[i] = W[i];
    for (int i = t; i < 4096; i += 128)
        sx[i >> 7][i & 127] = x[(size_t)(nb + (i >> 7)) * FDIM + (i & 127)];
    __syncthreads();
    const int h = t >> 5, e = t & 31;
    float wcol[32];
#pragma unroll
    for (int d = 0; d < 32; d++) wcol[d] = sW[h * 1024 + d * 32 + e];
    for (int nn = 0; nn < 32; nn++) {
        float acc = 0.0f;
#pragma unroll
        for (int d0 = 0; d0 < 32; d0++) {
            int d = (d0 + h * 8) & 31;  // stagger heads to spread LDS banks
            acc = fmaf(sx[nn][h * 32 + d], wcol[d], acc);
        }
        hp[(size_t)(nb + nn) * FDIM + t] = acc;
    }
}

// ---------------------------------------------------------------------------
// GCN aggregation (gather via CSR) + bias + relu.
// One WAVE per node; lane covers 2 features (float2). Edge indices + dinv
// prefetched 64-wide and broadcast via shfl (4x unrolled independent gathers).
// Graph->XCD swizzle: blockIdx%32 = graph -> graph slice stays L2-resident.
// ---------------------------------------------------------------------------
__global__ void agg_kernel(const float* __restrict__ hp, const float* __restrict__ b,
                           const float* __restrict__ dinv, const int* __restrict__ rowptr,
                           const int* __restrict__ rowcnt, const int* __restrict__ csr_src,
                           float* __restrict__ ha, int nper) {
    const int w = threadIdx.x >> 6;
    const int lane = threadIdx.x & 63;
    const int g = blockIdx.x & 31;
    const int chunk = blockIdx.x >> 5;
    const int i = g * nper + chunk * 4 + w;
    const float di = dinv[i];
    const float2* __restrict__ hp2 = (const float2*)hp;
    float2 self = hp2[(size_t)i * 64 + lane];
    float accx = self.x * di * di, accy = self.y * di * di;
    const int st = rowptr[i];
    const int c = rowcnt[i];
    for (int base = 0; base < c; base += 64) {
        const int cc = min(64, c - base);
        int idx = 0;
        float dv = 0.0f;
        if (lane < cc) {
            idx = csr_src[st + base + lane];
            dv = dinv[idx];
        }
        int j = 0;
        for (; j + 3 < cc; j += 4) {
            int s0 = __shfl(idx, j, 64);
            int s1 = __shfl(idx, j + 1, 64);
            int s2 = __shfl(idx, j + 2, 64);
            int s3 = __shfl(idx, j + 3, 64);
            float c0 = __shfl(dv, j, 64) * di;
            float c1 = __shfl(dv, j + 1, 64) * di;
            float c2 = __shfl(dv, j + 2, 64) * di;
            float c3 = __shfl(dv, j + 3, 64) * di;
            float2 v0 = hp2[(size_t)s0 * 64 + lane];
            float2 v1 = hp2[(size_t)s1 * 64 + lane];
            float2 v2 = hp2[(size_t)s2 * 64 + lane];
            float2 v3 = hp2[(size_t)s3 * 64 + lane];
            accx = fmaf(v0.x, c0, accx); accy = fmaf(v0.y, c0, accy);
            accx = fmaf(v1.x, c1, accx); accy = fmaf(v1.y, c1, accy);
            accx = fmaf(v2.x, c2, accx); accy = fmaf(v2.y, c2, accy);
            accx = fmaf(v3.x, c3, accx); accy = fmaf(v3.y, c3, accy);
        }
        for (; j < cc; j++) {
            int s = __shfl(idx, j, 64);
            float co = __shfl(dv, j, 64) * di;
            float2 v = hp2[(size_t)s * 64 + lane];
            accx = fmaf(v.x, co, accx); accy = fmaf(v.y, co, accy);
        }
    }
    float2 bb = ((const float2*)b)[lane];
    float2 o;
    o.x = fmaxf(accx + bb.x, 0.0f);
    o.y = fmaxf(accy + bb.y, 0.0f);
    ((float2*)ha)[(size_t)i * 64 + lane] = o;
}

// ---------------------------------------------------------------------------
// Attention score projection (float2, segmented head reductions).
// Also initializes the aggregated score with the self-loop term + bias:
// sc[i] = cs[i]*dinv[i]^2 + psb  (edge terms added by score_edge).
// ---------------------------------------------------------------------------
__global__ void attcs_kernel(const float* __restrict__ ha, const float* __restrict__ A,
                             const float* __restrict__ psW, const float* __restrict__ dinv,
                             const float* __restrict__ psb,
                             float* __restrict__ cs, float* __restrict__ sc_g) {
    const int wid = threadIdx.x >> 6;
    const int lane = threadIdx.x & 63;
    const int i = blockIdx.x * 4 + wid;
    float2 v = ((const float2*)ha)[(size_t)i * 64 + lane];
    float2 Av = ((const float2*)A)[lane];
    float2 Pv = ((const float2*)psW)[lane];
    float a = v.x * Av.x + v.y * Av.y;
    float p = v.x * Pv.x + v.y * Pv.y;
    for (int d = 8; d > 0; d >>= 1) {
        a += __shfl_down(a, d, 16);
        p += __shfl_down(p, d, 16);
    }
    float part = a * p;                  // heads at lanes 0,16,32,48
    part += __shfl_down(part, 16, 64);   // lane0+=lane16, lane32+=lane48
    part += __shfl_down(part, 32, 64);   // lane0+=lane32
    if (lane == 0) {
        cs[i] = part;
        float di = dinv[i];
        sc_g[i] = part * di * di + psb[0];
    }
}

// ---------------------------------------------------------------------------
// Edge-parallel score aggregation: sc[d] += cs[s]*dinv[s]*dinv[d].
// Random dst, avg 16 adds/node -> low atomic contention; spreads the gather
// latency over the whole GPU (vs 32-block serial chains).
// ---------------------------------------------------------------------------
__global__ void score_edge(const int* __restrict__ src, const int* __restrict__ dst,
                           const float* __restrict__ cs, const float* __restrict__ dinv,
                           float* __restrict__ sc_g) {
    int e = blockIdx.x * 256 + threadIdx.x;
    int s = src[e];
    if (s >= 0) {
        int d = dst[e];
        atomicAdd(&sc_g[d], cs[s] * dinv[s] * dinv[d]);
    }
}

// ---------------------------------------------------------------------------
// Per-graph top-k SET selection via 4-pass radix select (8 bits/pass) on
// sortable-uint keys. Order within the kept set is irrelevant downstream
// (readout is max/mean; aggregation is relabel-equivariant). ~10 barriers
// instead of the bitonic's 55.
// ---------------------------------------------------------------------------
__global__ void topk_kernel(const float* __restrict__ sc_g, int nper, int k,
                            int* __restrict__ nmap, int* __restrict__ perm,
                            float* __restrict__ mult) {
    __shared__ float sc[NPER0];
    __shared__ unsigned ukey[NPER0];
    __shared__ unsigned hist[256];
    __shared__ unsigned sel[2];  // [0]=prefix, [1]=need
    __shared__ int ctr[2];
    const int g = blockIdx.x, t = threadIdx.x;
    const int gnb = g * nper;
    for (int i = t; i < nper; i += 256) {
        float v = sc_g[gnb + i];
        sc[i] = v;
        unsigned u = __float_as_uint(v);
        u = (u & 0x80000000u) ? ~u : (u | 0x80000000u);  // ascending-sortable
        ukey[i] = u;
    }
    if (t == 0) { sel[0] = 0u; sel[1] = (unsigned)k; }
    for (int shift = 24; shift >= 0; shift -= 8) {
        hist[t] = 0u;
        __syncthreads();
        unsigned prefix = sel[0];
        for (int i = t; i < nper; i += 256) {
            unsigned u = ukey[i];
            if (shift == 24 || (u >> (shift + 8)) == (prefix >> (shift + 8)))
                atomicAdd(&hist[(u >> shift) & 255], 1u);
        }
        __syncthreads();
        if (t == 0) {
            unsigned need = sel[1], cum = 0;
            for (int d = 255; d >= 0; d--) {
                unsigned h = hist[d];
                if (cum + h >= need) {
                    sel[1] = need - cum;
                    sel[0] = prefix | ((unsigned)d << shift);
                    break;
                }
                cum += h;
            }
        }
        __syncthreads();
    }
    const unsigned T = sel[0];
    const int need = (int)sel[1];  // how many ==T to keep
    if (t == 0) { ctr[0] = 0; ctr[1] = k - need; }
    __syncthreads();
    for (int i = t; i < nper; i += 256) {
        unsigned u = ukey[i];
        int node = gnb + i;
        int newid = -1;
        if (u > T) {
            newid = g * k + atomicAdd(&ctr[0], 1);
        } else if (u == T) {
            int slot = atomicAdd(&ctr[1], 1);
            if (slot < k) newid = g * k + slot;
        }
        nmap[node] = newid;
        if (newid >= 0) {
            perm[newid] = node;
            mult[newid] = tanhf(sc[i]);
        }
    }
}

// ---------------------------------------------------------------------------
// Pooling gather (xn = h[perm]*tanh(score)) with partial readout.
// Grid: B*(k/PGJ) blocks, 128 threads; graph-swizzled (blk%32 = graph).
// ---------------------------------------------------------------------------
__global__ void poolgather_kernel(const float* __restrict__ ha, const int* __restrict__ perm,
                                  const float* __restrict__ mult, int k,
                                  float* __restrict__ xn,
                                  float* __restrict__ pmax, float* __restrict__ psum) {
    const int g = blockIdx.x & 31;
    const int c = blockIdx.x >> 5;
    const int f = threadIdx.x;
    const int base = g * k + c * PGJ;
    float vmax = -1e30f, vsum = 0.0f;
#pragma unroll
    for (int j = 0; j < PGJ; j++) {
        int newid = base + j;
        int old = perm[newid];
        float m = mult[newid];
        float v = ha[(size_t)old * FDIM + f] * m;
        xn[(size_t)newid * FDIM + f] = v;
        vmax = fmaxf(vmax, v);
        vsum += v;
    }
    const int pidx = g * (k / PGJ) + c;
    pmax[(size_t)pidx * FDIM + f] = vmax;
    psum[(size_t)pidx * FDIM + f] = vsum;
}

// ---------------------------------------------------------------------------
// Reduce partials into per-graph readout r[g, 0:128]=max, r[g,128:256]=mean.
// ---------------------------------------------------------------------------
__global__ void readout_reduce(const float* __restrict__ pmax, const float* __restrict__ psum,
                               int nchunks, int k, float* __restrict__ r, int accumulate) {
    const int g = blockIdx.x, f = threadIdx.x;
    float vmax = -1e30f, vsum = 0.0f;
    for (int c = 0; c < nchunks; c++) {
        size_t idx = (size_t)(g * nchunks + c) * FDIM + f;
        vmax = fmaxf(vmax, pmax[idx]);
        vsum += psum[idx];
    }
    float mean = vsum / (float)k;
    if (accumulate) {
        r[g * 256 + f] += vmax;
        r[g * 256 + 128 + f] += mean;
    } else {
        r[g * 256 + f] = vmax;
        r[g * 256 + 128 + f] = mean;
    }
}

// ---------------------------------------------------------------------------
// Edge remap after pooling, fused with next stage's degree count.
// Invalid edges carry src = -1 sentinel. cnt must be zeroed beforehand.
// ---------------------------------------------------------------------------
__global__ void remap_kernel(const int* __restrict__ src, const int* __restrict__ dst,
                             const int* __restrict__ nmap,
                             int* __restrict__ nsrc, int* __restrict__ ndst,
                             int* __restrict__ cnt) {
    const int e = blockIdx.x * 256 + threadIdx.x;
    int so = src[e];
    int ns = (so >= 0) ? nmap[so] : -1;
    int nd = nmap[dst[e]];
    bool valid = (ns >= 0) && (nd >= 0);
    nsrc[e] = valid ? ns : -1;
    ndst[e] = valid ? nd : 0;
    if (valid) atomicAdd(&cnt[nd], 1);
}

// ---------------------------------------------------------------------------
// Final MLP + log_softmax. One block per graph, 128 threads.
// ---------------------------------------------------------------------------
__global__ void final_mlp(const float* __restrict__ r,
                          const float* __restrict__ l1W, const float* __restrict__ l1b,
                          const float* __restrict__ l2W, const float* __restrict__ l2b,
                          const float* __restrict__ l3W, const float* __restrict__ l3b,
                          float* __restrict__ out) {
    __shared__ float sz[256], s1[128], s2[64], s3[10], red[2];
    const int g = blockIdx.x, t = threadIdx.x;
    sz[t] = r[g * 256 + t];
    sz[t + 128] = r[g * 256 + 128 + t];
    __syncthreads();
    float acc = l1b[t];
    for (int i = 0; i < 256; i++) acc = fmaf(sz[i], l1W[i * 128 + t], acc);
    s1[t] = fmaxf(acc, 0.0f);
    __syncthreads();
    if (t < 64) {
        float a2 = l2b[t];
        for (int i = 0; i < 128; i++) a2 = fmaf(s1[i], l2W[i * 64 + t], a2);
        s2[t] = fmaxf(a2, 0.0f);
    }
    __syncthreads();
    if (t < 10) {
        float a3 = l3b[t];
        for (int i = 0; i < 64; i++) a3 = fmaf(s2[i], l3W[i * 10 + t], a3);
        s3[t] = a3;
    }
    __syncthreads();
    if (t == 0) {
        float m = -1e30f;
        for (int c = 0; c < 10; c++) m = fmaxf(m, s3[c]);
        float sum = 0.0f;
        for (int c = 0; c < 10; c++) sum += expf(s3[c] - m);
        red[0] = m;
        red[1] = logf(sum);
    }
    __syncthreads();
    if (t < 10) out[g * 10 + t] = s3[t] - red[0] - red[1];
}

// ---------------------------------------------------------------------------
extern "C" void kernel_launch(void* const* d_in, const int* in_sizes, int n_in,
                              void* d_out, int out_size, void* d_ws, size_t ws_size,
                              hipStream_t stream) {
    const float* x    = (const float*)d_in[0];
    const int* src0   = (const int*)d_in[1];
    const int* dst0   = (const int*)d_in[2];
    const float* W1   = (const float*)d_in[3];
    const float* b1   = (const float*)d_in[4];
    const float* A1   = (const float*)d_in[5];
    const float* ps1W = (const float*)d_in[6];
    const float* ps1b = (const float*)d_in[7];
    const float* W2   = (const float*)d_in[8];
    const float* b2   = (const float*)d_in[9];
    const float* A2   = (const float*)d_in[10];
    const float* ps2W = (const float*)d_in[11];
    const float* ps2b = (const float*)d_in[12];
    const float* W3   = (const float*)d_in[13];
    const float* b3   = (const float*)d_in[14];
    const float* A3   = (const float*)d_in[15];
    const float* ps3W = (const float*)d_in[16];
    const float* ps3b = (const float*)d_in[17];
    const float* l1W  = (const float*)d_in[18];
    const float* l1b  = (const float*)d_in[19];
    const float* l2W  = (const float*)d_in[20];
    const float* l2b  = (const float*)d_in[21];
    const float* l3W  = (const float*)d_in[22];
    const float* l3b  = (const float*)d_in[23];
    float* out = (float*)d_out;

    char* ws = (char*)d_ws;
    size_t o = 0;
    auto alloc = [&](size_t bytes) -> void* {
        void* p = ws + o;
        o += (bytes + 255) & ~(size_t)255;
        return p;
    };
    float* hproj   = (float*)alloc((size_t)N0 * FDIM * 4);
    float* hact    = (float*)alloc((size_t)N0 * FDIM * 4);
    float* xn      = (float*)alloc((size_t)N0 * FDIM * 4);
    int*   cnt     = (int*)alloc(N0 * 4);
    float* dinv    = (float*)alloc(N0 * 4);
    int*   rowptr  = (int*)alloc(N0 * 4);
    int*   rowcnt  = (int*)alloc(N0 * 4);
    int*   csr_src = (int*)alloc(EDG * 4);
    float* cs      = (float*)alloc(N0 * 4);
    float* sc_g    = (float*)alloc(N0 * 4);
    int*   nmap    = (int*)alloc(N0 * 4);
    int*   perm    = (int*)alloc(BGR * K1 * 4);
    float* mult    = (float*)alloc(BGR * K1 * 4);
    float* r       = (float*)alloc(BGR * 256 * 4);
    int*   se1     = (int*)alloc(EDG * 4);
    int*   de1     = (int*)alloc(EDG * 4);
    int*   se2     = (int*)alloc(EDG * 4);
    int*   de2     = (int*)alloc(EDG * 4);
    float* pmax    = (float*)alloc((size_t)(BGR * K1 / PGJ) * FDIM * 4);
    float* psum    = (float*)alloc((size_t)(BGR * K1 / PGJ) * FDIM * 4);

    // ---------------- Stage 1: n=32768, nper=1024, k=512 ----------------
    zero_int<<<N0 / 256, 256, 0, stream>>>(cnt, N0);
    count_kernel<<<EDG / 256, 256, 0, stream>>>(src0, dst0, cnt);
    scan_kernel<<<BGR, 256, 0, stream>>>(cnt, NPER0, dinv, rowptr, rowcnt);
    scatter_kernel<<<EDG / 256, 256, 0, stream>>>(src0, dst0, rowptr, cnt, csr_src);
    proj_kernel<<<N0 / 32, 128, 0, stream>>>(x, W1, hproj);
    agg_kernel<<<N0 / 4, 256, 0, stream>>>(hproj, b1, dinv, rowptr, rowcnt, csr_src, hact, NPER0);
    attcs_kernel<<<N0 / 4, 256, 0, stream>>>(hact, A1, ps1W, dinv, ps1b, cs, sc_g);
    score_edge<<<EDG / 256, 256, 0, stream>>>(src0, dst0, cs, dinv, sc_g);
    topk_kernel<<<BGR, 256, 0, stream>>>(sc_g, NPER0, K1, nmap, perm, mult);
    poolgather_kernel<<<BGR * K1 / PGJ, 128, 0, stream>>>(hact, perm, mult, K1, xn, pmax, psum);
    readout_reduce<<<BGR, 128, 0, stream>>>(pmax, psum, K1 / PGJ, K1, r, 0);

    // ---------------- Stage 2: n=16384, nper=512, k=256 ----------------
    const int n1 = BGR * K1;
    zero_int<<<(n1 + 255) / 256, 256, 0, stream>>>(cnt, n1);
    remap_kernel<<<EDG / 256, 256, 0, stream>>>(src0, dst0, nmap, se1, de1, cnt);
    scan_kernel<<<BGR, 256, 0, stream>>>(cnt, K1, dinv, rowptr, rowcnt);
    scatter_kernel<<<EDG / 256, 256, 0, stream>>>(se1, de1, rowptr, cnt, csr_src);
    proj_kernel<<<n1 / 32, 128, 0, stream>>>(xn, W2, hproj);
    agg_kernel<<<n1 / 4, 256, 0, stream>>>(hproj, b2, dinv, rowptr, rowcnt, csr_src, hact, K1);
    attcs_kernel<<<n1 / 4, 256, 0, stream>>>(hact, A2, ps2W, dinv, ps2b, cs, sc_g);
    score_edge<<<EDG / 256, 256, 0, stream>>>(se1, de1, cs, dinv, sc_g);
    topk_kernel<<<BGR, 256, 0, stream>>>(sc_g, K1, K2, nmap, perm, mult);
    poolgather_kernel<<<BGR * K2 / PGJ, 128, 0, stream>>>(hact, perm, mult, K2, xn, pmax, psum);
    readout_reduce<<<BGR, 128, 0, stream>>>(pmax, psum, K2 / PGJ, K2, r, 1);

    // ---------------- Stage 3: n=8192, nper=256, k=128 ----------------
    const int n2 = BGR * K2;
    zero_int<<<(n2 + 255) / 256, 256, 0, stream>>>(cnt, n2);
    remap_kernel<<<EDG / 256, 256, 0, stream>>>(se1, de1, nmap, se2, de2, cnt);
    scan_kernel<<<BGR, 256, 0, stream>>>(cnt, K2, dinv, rowptr, rowcnt);
    scatter_kernel<<<EDG / 256, 256, 0, stream>>>(se2, de2, rowptr, cnt, csr_src);
    proj_kernel<<<n2 / 32, 128, 0, stream>>>(xn, W3, hproj);
    agg_kernel<<<n2 / 4, 256, 0, stream>>>(hproj, b3, dinv, rowptr, rowcnt, csr_src, hact, K2);
    attcs_kernel<<<n2 / 4, 256, 0, stream>>>(hact, A3, ps3W, dinv, ps3b, cs, sc_g);
    score_edge<<<EDG / 256, 256, 0, stream>>>(se2, de2, cs, dinv, sc_g);
    topk_kernel<<<BGR, 256, 0, stream>>>(sc_g, K2, K3, nmap, perm, mult);
    poolgather_kernel<<<BGR * K3 / PGJ, 128, 0, stream>>>(hact, perm, mult, K3, xn, pmax, psum);
    readout_reduce<<<BGR, 128, 0, stream>>>(pmax, psum, K3 / PGJ, K3, r, 1);

    // ---------------- Final MLP ----------------
    final_mlp<<<BGR, 128, 0, stream>>>(r, l1W, l1b, l2W, l2b, l3W, l3b, out);

    (void)in_sizes; (void)n_in; (void)out_size; (void)ws_size;
}

// Round 6
// 416.028 us; speedup vs baseline: 1.3283x; 1.3283x over previous
//
#include <hip/hip_runtime.h>
#include <math.h>

#define BGR 32
#define NPER0 1024
#define N0 (BGR * NPER0)
#define FDIM 128
#define EDG 524288
#define EPG (EDG / BGR)
#define K1 512
#define K2 256
#define K3 128
#define PGJ 8  // kept nodes per poolgather block

// ---------------------------------------------------------------------------
// Parallel CSR build: zero -> count (atomic, 1 thread/edge) -> per-graph scan
// -> scatter (atomic cursor, 1 thread/edge). Edge validity = (src[e] >= 0).
// ---------------------------------------------------------------------------
__global__ void zero_int(int* __restrict__ p, int n) {
    int i = blockIdx.x * 256 + threadIdx.x;
    if (i < n) p[i] = 0;
}

__global__ void count_kernel(const int* __restrict__ src, const int* __restrict__ dst,
                             int* __restrict__ cnt) {
    int e = blockIdx.x * 256 + threadIdx.x;
    int s = src[e];
    if (s >= 0) atomicAdd(&cnt[dst[e]], 1);
}

// Per-graph exclusive scan of cnt -> rowptr; writes dinv/rowcnt; zeroes cnt
// (reused as scatter cursor). 32 blocks x 256 threads over nper<=1024 elems.
__global__ void scan_kernel(int* __restrict__ cnt, int nper,
                            float* __restrict__ dinv,
                            int* __restrict__ rowptr, int* __restrict__ rowcnt) {
    __shared__ int scnt[NPER0];
    __shared__ int soff[NPER0];
    __shared__ int psum[256];
    const int g = blockIdx.x, t = threadIdx.x;
    const int gnb = g * nper, ebase = g * EPG;
    for (int i = t; i < nper; i += 256) scnt[i] = cnt[gnb + i];
    __syncthreads();
    const int S = nper >> 8;  // 4, 2, or 1
    const int b0 = t * S;
    int loc = 0;
    for (int q = 0; q < S; q++) loc += scnt[b0 + q];
    psum[t] = loc;
    __syncthreads();
    if (t == 0) {
        int run = 0;
        for (int i = 0; i < 256; i++) { int v = psum[i]; psum[i] = run; run += v; }
    }
    __syncthreads();
    int run = psum[t];
    for (int q = 0; q < S; q++) { soff[b0 + q] = run; run += scnt[b0 + q]; }
    __syncthreads();
    for (int i = t; i < nper; i += 256) {
        int c = scnt[i];
        dinv[gnb + i] = rsqrtf((float)c + 1.0f);
        rowptr[gnb + i] = ebase + soff[i];
        rowcnt[gnb + i] = c;
        cnt[gnb + i] = 0;  // cursor for scatter
    }
}

__global__ void scatter_kernel(const int* __restrict__ src, const int* __restrict__ dst,
                               const int* __restrict__ rowptr, int* __restrict__ cursor,
                               int* __restrict__ csr_src) {
    int e = blockIdx.x * 256 + threadIdx.x;
    int s = src[e];
    if (s >= 0) {
        int d = dst[e];
        int p = atomicAdd(&cursor[d], 1);
        csr_src[rowptr[d] + p] = s;
    }
}

// ---------------------------------------------------------------------------
// Per-head projection: h[i, h*32+e] = sum_d x[i, h*32+d] * W[h, d, e].
// Block = 128 threads (one output feature each), 32 nodes per block.
// ---------------------------------------------------------------------------
__global__ void proj_kernel(const float* __restrict__ x, const float* __restrict__ W,
                            float* __restrict__ hp) {
    __shared__ float sW[4096];
    __shared__ float sx[32][128];
    const int t = threadIdx.x;
    const int nb = blockIdx.x * 32;
    for (int i = t; i < 4096; i += 128) sW[i] = W[i];
    for (int i = t; i < 4096; i += 128)
        sx[i >> 7][i & 127] = x[(size_t)(nb + (i >> 7)) * FDIM + (i & 127)];
    __syncthreads();
    const int h = t >> 5, e = t & 31;
    float wcol[32];
#pragma unroll
    for (int d = 0; d < 32; d++) wcol[d] = sW[h * 1024 + d * 32 + e];
    for (int nn = 0; nn < 32; nn++) {
        float acc = 0.0f;
#pragma unroll
        for (int d0 = 0; d0 < 32; d0++) {
            int d = (d0 + h * 8) & 31;  // stagger heads to spread LDS banks
            acc = fmaf(sx[nn][h * 32 + d], wcol[d], acc);
        }
        hp[(size_t)(nb + nn) * FDIM + t] = acc;
    }
}

// ---------------------------------------------------------------------------
// GCN aggregation (gather via CSR) + bias + relu.
// One WAVE per node; lane covers 2 features (float2). Edge indices + dinv
// prefetched 64-wide and broadcast via shfl (4x unrolled independent gathers).
// Graph->XCD swizzle: blockIdx%32 = graph -> graph slice stays L2-resident.
// ---------------------------------------------------------------------------
__global__ void agg_kernel(const float* __restrict__ hp, const float* __restrict__ b,
                           const float* __restrict__ dinv, const int* __restrict__ rowptr,
                           const int* __restrict__ rowcnt, const int* __restrict__ csr_src,
                           float* __restrict__ ha, int nper) {
    const int w = threadIdx.x >> 6;
    const int lane = threadIdx.x & 63;
    const int g = blockIdx.x & 31;
    const int chunk = blockIdx.x >> 5;
    const int i = g * nper + chunk * 4 + w;
    const float di = dinv[i];
    const float2* __restrict__ hp2 = (const float2*)hp;
    float2 self = hp2[(size_t)i * 64 + lane];
    float accx = self.x * di * di, accy = self.y * di * di;
    const int st = rowptr[i];
    const int c = rowcnt[i];
    for (int base = 0; base < c; base += 64) {
        const int cc = min(64, c - base);
        int idx = 0;
        float dv = 0.0f;
        if (lane < cc) {
            idx = csr_src[st + base + lane];
            dv = dinv[idx];
        }
        int j = 0;
        for (; j + 3 < cc; j += 4) {
            int s0 = __shfl(idx, j, 64);
            int s1 = __shfl(idx, j + 1, 64);
            int s2 = __shfl(idx, j + 2, 64);
            int s3 = __shfl(idx, j + 3, 64);
            float c0 = __shfl(dv, j, 64) * di;
            float c1 = __shfl(dv, j + 1, 64) * di;
            float c2 = __shfl(dv, j + 2, 64) * di;
            float c3 = __shfl(dv, j + 3, 64) * di;
            float2 v0 = hp2[(size_t)s0 * 64 + lane];
            float2 v1 = hp2[(size_t)s1 * 64 + lane];
            float2 v2 = hp2[(size_t)s2 * 64 + lane];
            float2 v3 = hp2[(size_t)s3 * 64 + lane];
            accx = fmaf(v0.x, c0, accx); accy = fmaf(v0.y, c0, accy);
            accx = fmaf(v1.x, c1, accx); accy = fmaf(v1.y, c1, accy);
            accx = fmaf(v2.x, c2, accx); accy = fmaf(v2.y, c2, accy);
            accx = fmaf(v3.x, c3, accx); accy = fmaf(v3.y, c3, accy);
        }
        for (; j < cc; j++) {
            int s = __shfl(idx, j, 64);
            float co = __shfl(dv, j, 64) * di;
            float2 v = hp2[(size_t)s * 64 + lane];
            accx = fmaf(v.x, co, accx); accy = fmaf(v.y, co, accy);
        }
    }
    float2 bb = ((const float2*)b)[lane];
    float2 o;
    o.x = fmaxf(accx + bb.x, 0.0f);
    o.y = fmaxf(accy + bb.y, 0.0f);
    ((float2*)ha)[(size_t)i * 64 + lane] = o;
}

// ---------------------------------------------------------------------------
// Attention score projection (float2, segmented head reductions).
// cs[i] = sum_h (x_h . A_h) * (x_h . psW_h); head h = lanes [16h,16h+16).
// ---------------------------------------------------------------------------
__global__ void attcs_kernel(const float* __restrict__ ha, const float* __restrict__ A,
                             const float* __restrict__ psW, float* __restrict__ cs) {
    const int wid = threadIdx.x >> 6;
    const int lane = threadIdx.x & 63;
    const int i = blockIdx.x * 4 + wid;
    float2 v = ((const float2*)ha)[(size_t)i * 64 + lane];
    float2 Av = ((const float2*)A)[lane];
    float2 Pv = ((const float2*)psW)[lane];
    float a = v.x * Av.x + v.y * Av.y;
    float p = v.x * Pv.x + v.y * Pv.y;
    for (int d = 8; d > 0; d >>= 1) {
        a += __shfl_down(a, d, 16);
        p += __shfl_down(p, d, 16);
    }
    float part = a * p;                  // heads at lanes 0,16,32,48
    part += __shfl_down(part, 16, 64);   // lane0+=lane16, lane32+=lane48
    part += __shfl_down(part, 32, 64);   // lane0+=lane32
    if (lane == 0) cs[i] = part;
}

// ---------------------------------------------------------------------------
// Fused score-aggregation + per-graph top-k SET via 4-pass radix select with
// PARALLEL digit selection (wave shfl suffix-scan over 256 bins; the serial
// t==0 bin walk was ~50us of LDS latency). Order within the kept set is
// irrelevant downstream (readout max/mean; aggregation relabel-equivariant).
// ---------------------------------------------------------------------------
__global__ void topk_kernel(const float* __restrict__ cs, const float* __restrict__ dinv,
                            const int* __restrict__ rowptr, const int* __restrict__ rowcnt,
                            const int* __restrict__ csr_src, const float* __restrict__ psb,
                            int nper, int k, int* __restrict__ nmap, int* __restrict__ perm,
                            float* __restrict__ mult) {
    __shared__ float sc[NPER0];
    __shared__ unsigned ukey[NPER0];
    __shared__ unsigned hist[256];
    __shared__ unsigned wtot[4];
    __shared__ unsigned sel[2];  // [0]=prefix/threshold, [1]=need (ties to keep)
    __shared__ int ctr[2];
    const int g = blockIdx.x, t = threadIdx.x;
    const int w = t >> 6, l = t & 63;
    const int gnb = g * nper;
    const float pb = psb[0];
    // score aggregation (CSR gather; ~16 edges/node avg)
    for (int i = t; i < nper; i += 256) {
        int node = gnb + i;
        float di = dinv[node];
        float acc = cs[node] * di * di;
        int st = rowptr[node], c = rowcnt[node];
        for (int j = 0; j < c; j++) {
            int s = csr_src[st + j];
            acc = fmaf(cs[s], dinv[s] * di, acc);
        }
        float v = acc + pb;
        sc[i] = v;
        unsigned u = __float_as_uint(v);
        u = (u & 0x80000000u) ? ~u : (u | 0x80000000u);  // ascending-sortable
        ukey[i] = u;
    }
    if (t == 0) { sel[0] = 0u; sel[1] = (unsigned)k; }
    __syncthreads();
    for (int shift = 24; shift >= 0; shift -= 8) {
        hist[t] = 0u;
        __syncthreads();
        const unsigned prefix = sel[0];
        const unsigned need = sel[1];
        for (int i = t; i < nper; i += 256) {
            unsigned u = ukey[i];
            if (shift == 24 || (u >> (shift + 8)) == (prefix >> (shift + 8)))
                atomicAdd(&hist[(u >> shift) & 255], 1u);
        }
        __syncthreads();
        const unsigned h = hist[t];
        // suffix-inclusive scan within wave (bins t..t|63): no barriers
        unsigned s = h;
#pragma unroll
        for (int off = 1; off < 64; off <<= 1) {
            unsigned v = __shfl_down(s, off, 64);
            if (l + off < 64) s += v;
        }
        if (l == 0) wtot[w] = s;
        __syncthreads();
        unsigned add = 0;
        for (int ww = w + 1; ww < 4; ww++) add += wtot[ww];
        const unsigned sfx = s + add;  // #keys with digit >= t (within prefix)
        const unsigned gtr = sfx - h;  // #keys with digit >  t
        if (sfx >= need && gtr < need) {  // exactly one thread
            sel[0] = prefix | ((unsigned)t << shift);
            sel[1] = need - gtr;
        }
        __syncthreads();
    }
    const unsigned T = sel[0];
    const int need = (int)sel[1];  // how many ==T to keep
    if (t == 0) { ctr[0] = 0; ctr[1] = k - need; }
    __syncthreads();
    for (int i = t; i < nper; i += 256) {
        unsigned u = ukey[i];
        int node = gnb + i;
        int newid = -1;
        if (u > T) {
            newid = g * k + atomicAdd(&ctr[0], 1);
        } else if (u == T) {
            int slot = atomicAdd(&ctr[1], 1);
            if (slot < k) newid = g * k + slot;
        }
        nmap[node] = newid;
        if (newid >= 0) {
            perm[newid] = node;
            mult[newid] = tanhf(sc[i]);
        }
    }
}

// ---------------------------------------------------------------------------
// Pooling gather (xn = h[perm]*tanh(score)) with partial readout.
// Grid: B*(k/PGJ) blocks, 128 threads; graph-swizzled (blk%32 = graph).
// ---------------------------------------------------------------------------
__global__ void poolgather_kernel(const float* __restrict__ ha, const int* __restrict__ perm,
                                  const float* __restrict__ mult, int k,
                                  float* __restrict__ xn,
                                  float* __restrict__ pmax, float* __restrict__ psum) {
    const int g = blockIdx.x & 31;
    const int c = blockIdx.x >> 5;
    const int f = threadIdx.x;
    const int base = g * k + c * PGJ;
    float vmax = -1e30f, vsum = 0.0f;
#pragma unroll
    for (int j = 0; j < PGJ; j++) {
        int newid = base + j;
        int old = perm[newid];
        float m = mult[newid];
        float v = ha[(size_t)old * FDIM + f] * m;
        xn[(size_t)newid * FDIM + f] = v;
        vmax = fmaxf(vmax, v);
        vsum += v;
    }
    const int pidx = g * (k / PGJ) + c;
    pmax[(size_t)pidx * FDIM + f] = vmax;
    psum[(size_t)pidx * FDIM + f] = vsum;
}

// ---------------------------------------------------------------------------
// Reduce partials into per-graph readout r[g, 0:128]=max, r[g,128:256]=mean.
// ---------------------------------------------------------------------------
__global__ void readout_reduce(const float* __restrict__ pmax, const float* __restrict__ psum,
                               int nchunks, int k, float* __restrict__ r, int accumulate) {
    const int g = blockIdx.x, f = threadIdx.x;
    float vmax = -1e30f, vsum = 0.0f;
    for (int c = 0; c < nchunks; c++) {
        size_t idx = (size_t)(g * nchunks + c) * FDIM + f;
        vmax = fmaxf(vmax, pmax[idx]);
        vsum += psum[idx];
    }
    float mean = vsum / (float)k;
    if (accumulate) {
        r[g * 256 + f] += vmax;
        r[g * 256 + 128 + f] += mean;
    } else {
        r[g * 256 + f] = vmax;
        r[g * 256 + 128 + f] = mean;
    }
}

// ---------------------------------------------------------------------------
// Edge remap after pooling, fused with next stage's degree count.
// Invalid edges carry src = -1 sentinel. cnt must be zeroed beforehand.
// ---------------------------------------------------------------------------
__global__ void remap_kernel(const int* __restrict__ src, const int* __restrict__ dst,
                             const int* __restrict__ nmap,
                             int* __restrict__ nsrc, int* __restrict__ ndst,
                             int* __restrict__ cnt) {
    const int e = blockIdx.x * 256 + threadIdx.x;
    int so = src[e];
    int ns = (so >= 0) ? nmap[so] : -1;
    int nd = nmap[dst[e]];
    bool valid = (ns >= 0) && (nd >= 0);
    nsrc[e] = valid ? ns : -1;
    ndst[e] = valid ? nd : 0;
    if (valid) atomicAdd(&cnt[nd], 1);
}

// ---------------------------------------------------------------------------
// Final MLP + log_softmax. One block per graph, 128 threads.
// ---------------------------------------------------------------------------
__global__ void final_mlp(const float* __restrict__ r,
                          const float* __restrict__ l1W, const float* __restrict__ l1b,
                          const float* __restrict__ l2W, const float* __restrict__ l2b,
                          const float* __restrict__ l3W, const float* __restrict__ l3b,
                          float* __restrict__ out) {
    __shared__ float sz[256], s1[128], s2[64], s3[10], red[2];
    const int g = blockIdx.x, t = threadIdx.x;
    sz[t] = r[g * 256 + t];
    sz[t + 128] = r[g * 256 + 128 + t];
    __syncthreads();
    float acc = l1b[t];
    for (int i = 0; i < 256; i++) acc = fmaf(sz[i], l1W[i * 128 + t], acc);
    s1[t] = fmaxf(acc, 0.0f);
    __syncthreads();
    if (t < 64) {
        float a2 = l2b[t];
        for (int i = 0; i < 128; i++) a2 = fmaf(s1[i], l2W[i * 64 + t], a2);
        s2[t] = fmaxf(a2, 0.0f);
    }
    __syncthreads();
    if (t < 10) {
        float a3 = l3b[t];
        for (int i = 0; i < 64; i++) a3 = fmaf(s2[i], l3W[i * 10 + t], a3);
        s3[t] = a3;
    }
    __syncthreads();
    if (t == 0) {
        float m = -1e30f;
        for (int c = 0; c < 10; c++) m = fmaxf(m, s3[c]);
        float sum = 0.0f;
        for (int c = 0; c < 10; c++) sum += expf(s3[c] - m);
        red[0] = m;
        red[1] = logf(sum);
    }
    __syncthreads();
    if (t < 10) out[g * 10 + t] = s3[t] - red[0] - red[1];
}

// ---------------------------------------------------------------------------
extern "C" void kernel_launch(void* const* d_in, const int* in_sizes, int n_in,
                              void* d_out, int out_size, void* d_ws, size_t ws_size,
                              hipStream_t stream) {
    const float* x    = (const float*)d_in[0];
    const int* src0   = (const int*)d_in[1];
    const int* dst0   = (const int*)d_in[2];
    const float* W1   = (const float*)d_in[3];
    const float* b1   = (const float*)d_in[4];
    const float* A1   = (const float*)d_in[5];
    const float* ps1W = (const float*)d_in[6];
    const float* ps1b = (const float*)d_in[7];
    const float* W2   = (const float*)d_in[8];
    const float* b2   = (const float*)d_in[9];
    const float* A2   = (const float*)d_in[10];
    const float* ps2W = (const float*)d_in[11];
    const float* ps2b = (const float*)d_in[12];
    const float* W3   = (const float*)d_in[13];
    const float* b3   = (const float*)d_in[14];
    const float* A3   = (const float*)d_in[15];
    const float* ps3W = (const float*)d_in[16];
    const float* ps3b = (const float*)d_in[17];
    const float* l1W  = (const float*)d_in[18];
    const float* l1b  = (const float*)d_in[19];
    const float* l2W  = (const float*)d_in[20];
    const float* l2b  = (const float*)d_in[21];
    const float* l3W  = (const float*)d_in[22];
    const float* l3b  = (const float*)d_in[23];
    float* out = (float*)d_out;

    char* ws = (char*)d_ws;
    size_t o = 0;
    auto alloc = [&](size_t bytes) -> void* {
        void* p = ws + o;
        o += (bytes + 255) & ~(size_t)255;
        return p;
    };
    float* hproj   = (float*)alloc((size_t)N0 * FDIM * 4);
    float* hact    = (float*)alloc((size_t)N0 * FDIM * 4);
    float* xn      = (float*)alloc((size_t)N0 * FDIM * 4);
    int*   cnt     = (int*)alloc(N0 * 4);
    float* dinv    = (float*)alloc(N0 * 4);
    int*   rowptr  = (int*)alloc(N0 * 4);
    int*   rowcnt  = (int*)alloc(N0 * 4);
    int*   csr_src = (int*)alloc(EDG * 4);
    float* cs      = (float*)alloc(N0 * 4);
    int*   nmap    = (int*)alloc(N0 * 4);
    int*   perm    = (int*)alloc(BGR * K1 * 4);
    float* mult    = (float*)alloc(BGR * K1 * 4);
    float* r       = (float*)alloc(BGR * 256 * 4);
    int*   se1     = (int*)alloc(EDG * 4);
    int*   de1     = (int*)alloc(EDG * 4);
    int*   se2     = (int*)alloc(EDG * 4);
    int*   de2     = (int*)alloc(EDG * 4);
    float* pmax    = (float*)alloc((size_t)(BGR * K1 / PGJ) * FDIM * 4);
    float* psum    = (float*)alloc((size_t)(BGR * K1 / PGJ) * FDIM * 4);

    // ---------------- Stage 1: n=32768, nper=1024, k=512 ----------------
    zero_int<<<N0 / 256, 256, 0, stream>>>(cnt, N0);
    count_kernel<<<EDG / 256, 256, 0, stream>>>(src0, dst0, cnt);
    scan_kernel<<<BGR, 256, 0, stream>>>(cnt, NPER0, dinv, rowptr, rowcnt);
    scatter_kernel<<<EDG / 256, 256, 0, stream>>>(src0, dst0, rowptr, cnt, csr_src);
    proj_kernel<<<N0 / 32, 128, 0, stream>>>(x, W1, hproj);
    agg_kernel<<<N0 / 4, 256, 0, stream>>>(hproj, b1, dinv, rowptr, rowcnt, csr_src, hact, NPER0);
    attcs_kernel<<<N0 / 4, 256, 0, stream>>>(hact, A1, ps1W, cs);
    topk_kernel<<<BGR, 256, 0, stream>>>(cs, dinv, rowptr, rowcnt, csr_src, ps1b,
                                         NPER0, K1, nmap, perm, mult);
    poolgather_kernel<<<BGR * K1 / PGJ, 128, 0, stream>>>(hact, perm, mult, K1, xn, pmax, psum);
    readout_reduce<<<BGR, 128, 0, stream>>>(pmax, psum, K1 / PGJ, K1, r, 0);

    // ---------------- Stage 2: n=16384, nper=512, k=256 ----------------
    const int n1 = BGR * K1;
    zero_int<<<(n1 + 255) / 256, 256, 0, stream>>>(cnt, n1);
    remap_kernel<<<EDG / 256, 256, 0, stream>>>(src0, dst0, nmap, se1, de1, cnt);
    scan_kernel<<<BGR, 256, 0, stream>>>(cnt, K1, dinv, rowptr, rowcnt);
    scatter_kernel<<<EDG / 256, 256, 0, stream>>>(se1, de1, rowptr, cnt, csr_src);
    proj_kernel<<<n1 / 32, 128, 0, stream>>>(xn, W2, hproj);
    agg_kernel<<<n1 / 4, 256, 0, stream>>>(hproj, b2, dinv, rowptr, rowcnt, csr_src, hact, K1);
    attcs_kernel<<<n1 / 4, 256, 0, stream>>>(hact, A2, ps2W, cs);
    topk_kernel<<<BGR, 256, 0, stream>>>(cs, dinv, rowptr, rowcnt, csr_src, ps2b,
                                         K1, K2, nmap, perm, mult);
    poolgather_kernel<<<BGR * K2 / PGJ, 128, 0, stream>>>(hact, perm, mult, K2, xn, pmax, psum);
    readout_reduce<<<BGR, 128, 0, stream>>>(pmax, psum, K2 / PGJ, K2, r, 1);

    // ---------------- Stage 3: n=8192, nper=256, k=128 ----------------
    const int n2 = BGR * K2;
    zero_int<<<(n2 + 255) / 256, 256, 0, stream>>>(cnt, n2);
    remap_kernel<<<EDG / 256, 256, 0, stream>>>(se1, de1, nmap, se2, de2, cnt);
    scan_kernel<<<BGR, 256, 0, stream>>>(cnt, K2, dinv, rowptr, rowcnt);
    scatter_kernel<<<EDG / 256, 256, 0, stream>>>(se2, de2, rowptr, cnt, csr_src);
    proj_kernel<<<n2 / 32, 128, 0, stream>>>(xn, W3, hproj);
    agg_kernel<<<n2 / 4, 256, 0, stream>>>(hproj, b3, dinv, rowptr, rowcnt, csr_src, hact, K2);
    attcs_kernel<<<n2 / 4, 256, 0, stream>>>(hact, A3, ps3W, cs);
    topk_kernel<<<BGR, 256, 0, stream>>>(cs, dinv, rowptr, rowcnt, csr_src, ps3b,
                                         K2, K3, nmap, perm, mult);
    poolgather_kernel<<<BGR * K3 / PGJ, 128, 0, stream>>>(hact, perm, mult, K3, xn, pmax, psum);
    readout_reduce<<<BGR, 128, 0, stream>>>(pmax, psum, K3 / PGJ, K3, r, 1);

    // ---------------- Final MLP ----------------
    final_mlp<<<BGR, 128, 0, stream>>>(r, l1W, l1b, l2W, l2b, l3W, l3b, out);

    (void)in_sizes; (void)n_in; (void)out_size; (void)ws_size;
}

// Round 7
// 378.235 us; speedup vs baseline: 1.4610x; 1.0999x over previous
//
#include <hip/hip_runtime.h>
#include <math.h>

#define BGR 32
#define NPER0 1024
#define N0 (BGR * NPER0)
#define FDIM 128
#define EDG 524288
#define EPG (EDG / BGR)
#define K1 512
#define K2 256
#define K3 128
#define EBLK (EDG / 256)  // edge-parallel blocks (2048)

// Order-preserving float<->uint encoding (for atomicMax on floats).
__device__ __forceinline__ unsigned enc_f(float v) {
    unsigned u = __float_as_uint(v);
    return (u & 0x80000000u) ? ~u : (u | 0x80000000u);
}
__device__ __forceinline__ float dec_f(unsigned u) {
    return (u & 0x80000000u) ? __uint_as_float(u ^ 0x80000000u) : __uint_as_float(~u);
}

// ---------------------------------------------------------------------------
// Per-call zero of stage-1 degree counters + all readout accumulators.
// ---------------------------------------------------------------------------
__global__ void zero_all(int* __restrict__ cntA, unsigned* __restrict__ rmax,
                         float* __restrict__ rsum) {
    int i = blockIdx.x * 256 + threadIdx.x;
    if (i < N0) cntA[i] = 0;
    if (i < 3 * BGR * FDIM) { rmax[i] = 0u; rsum[i] = 0.0f; }
}

// ---------------------------------------------------------------------------
// Fat kernel: edge-degree count (blocks < EBLK) | projection (rest).
// proj: h[i, f] = sum_d x[i, (f>>5)*32+d] * W[f>>5, d, f&31]; 256 threads,
// 32 nodes/block, thread = (feature f, node-half).
// ---------------------------------------------------------------------------
__global__ void count_proj(const int* __restrict__ src, const int* __restrict__ dst,
                           int* __restrict__ cnt,
                           const float* __restrict__ x, const float* __restrict__ W,
                           float* __restrict__ hp) {
    __shared__ float sW[4096];
    __shared__ float sx[32][128];
    const int t = threadIdx.x;
    if (blockIdx.x < EBLK) {
        int e = blockIdx.x * 256 + t;
        int s = src[e];
        if (s >= 0) atomicAdd(&cnt[dst[e]], 1);
        return;
    }
    const int nb = (blockIdx.x - EBLK) * 32;
    for (int i = t; i < 4096; i += 256) sW[i] = W[i];
    for (int i = t; i < 4096; i += 256)
        sx[i >> 7][i & 127] = x[(size_t)(nb + (i >> 7)) * FDIM + (i & 127)];
    __syncthreads();
    const int f = t & 127, half = t >> 7;
    const int h = f >> 5, e = f & 31;
    float wcol[32];
#pragma unroll
    for (int d = 0; d < 32; d++) wcol[d] = sW[h * 1024 + d * 32 + e];
    for (int nn = half; nn < 32; nn += 2) {
        float acc = 0.0f;
#pragma unroll
        for (int d0 = 0; d0 < 32; d0++) {
            int d = (d0 + h * 8) & 31;
            acc = fmaf(sx[nn][h * 32 + d], wcol[d], acc);
        }
        hp[(size_t)(nb + nn) * FDIM + f] = acc;
    }
}

// ---------------------------------------------------------------------------
// Fat kernel: CSR scatter (blocks < EBLK) | projection (rest). Stages 2/3.
// ---------------------------------------------------------------------------
__global__ void scatter_proj(const int* __restrict__ src, const int* __restrict__ dst,
                             const int* __restrict__ rowptr, int* __restrict__ cursor,
                             int* __restrict__ csr_src,
                             const float* __restrict__ x, const float* __restrict__ W,
                             float* __restrict__ hp) {
    __shared__ float sW[4096];
    __shared__ float sx[32][128];
    const int t = threadIdx.x;
    if (blockIdx.x < EBLK) {
        int e = blockIdx.x * 256 + t;
        int s = src[e];
        if (s >= 0) {
            int d = dst[e];
            int p = atomicAdd(&cursor[d], 1);
            csr_src[rowptr[d] + p] = s;
        }
        return;
    }
    const int nb = (blockIdx.x - EBLK) * 32;
    for (int i = t; i < 4096; i += 256) sW[i] = W[i];
    for (int i = t; i < 4096; i += 256)
        sx[i >> 7][i & 127] = x[(size_t)(nb + (i >> 7)) * FDIM + (i & 127)];
    __syncthreads();
    const int f = t & 127, half = t >> 7;
    const int h = f >> 5, e = f & 31;
    float wcol[32];
#pragma unroll
    for (int d = 0; d < 32; d++) wcol[d] = sW[h * 1024 + d * 32 + e];
    for (int nn = half; nn < 32; nn += 2) {
        float acc = 0.0f;
#pragma unroll
        for (int d0 = 0; d0 < 32; d0++) {
            int d = (d0 + h * 8) & 31;
            acc = fmaf(sx[nn][h * 32 + d], wcol[d], acc);
        }
        hp[(size_t)(nb + nn) * FDIM + f] = acc;
    }
}

// ---------------------------------------------------------------------------
// Per-graph exclusive scan of cnt -> rowptr; writes dinv/rowcnt; zeroes cnt
// (reused as scatter cursor) and the NEXT stage's cnt buffer.
// ---------------------------------------------------------------------------
__global__ void scan_kernel(int* __restrict__ cnt, int nper,
                            float* __restrict__ dinv,
                            int* __restrict__ rowptr, int* __restrict__ rowcnt,
                            int* __restrict__ cnt_next, int n_next) {
    __shared__ int scnt[NPER0];
    __shared__ int soff[NPER0];
    __shared__ int psum[256];
    const int g = blockIdx.x, t = threadIdx.x;
    const int gnb = g * nper, ebase = g * EPG;
    for (int i = blockIdx.x * 256 + t; i < n_next; i += BGR * 256) cnt_next[i] = 0;
    for (int i = t; i < nper; i += 256) scnt[i] = cnt[gnb + i];
    __syncthreads();
    const int S = nper >> 8;  // 4, 2, or 1
    const int b0 = t * S;
    int loc = 0;
    for (int q = 0; q < S; q++) loc += scnt[b0 + q];
    psum[t] = loc;
    __syncthreads();
    if (t == 0) {
        int run = 0;
        for (int i = 0; i < 256; i++) { int v = psum[i]; psum[i] = run; run += v; }
    }
    __syncthreads();
    int run = psum[t];
    for (int q = 0; q < S; q++) { soff[b0 + q] = run; run += scnt[b0 + q]; }
    __syncthreads();
    for (int i = t; i < nper; i += 256) {
        int c = scnt[i];
        dinv[gnb + i] = rsqrtf((float)c + 1.0f);
        rowptr[gnb + i] = ebase + soff[i];
        rowcnt[gnb + i] = c;
        cnt[gnb + i] = 0;  // cursor for scatter
    }
}

// ---------------------------------------------------------------------------
// GCN aggregation (gather via CSR) + bias + relu, FUSED with the attention
// score projection (the wave holds the full 128-feature row in registers).
// One WAVE per node; lane covers 2 features (float2); shfl-broadcast edge
// prefetch (4x unrolled). Graph->XCD swizzle: blockIdx%32 = graph.
// ---------------------------------------------------------------------------
__global__ void agg_kernel(const float* __restrict__ hp, const float* __restrict__ b,
                           const float* __restrict__ dinv, const int* __restrict__ rowptr,
                           const int* __restrict__ rowcnt, const int* __restrict__ csr_src,
                           const float* __restrict__ A, const float* __restrict__ psW,
                           float* __restrict__ ha, float* __restrict__ cs, int nper) {
    const int w = threadIdx.x >> 6;
    const int lane = threadIdx.x & 63;
    const int g = blockIdx.x & 31;
    const int chunk = blockIdx.x >> 5;
    const int i = g * nper + chunk * 4 + w;
    const float di = dinv[i];
    const float2* __restrict__ hp2 = (const float2*)hp;
    float2 self = hp2[(size_t)i * 64 + lane];
    float accx = self.x * di * di, accy = self.y * di * di;
    const int st = rowptr[i];
    const int c = rowcnt[i];
    for (int base = 0; base < c; base += 64) {
        const int cc = min(64, c - base);
        int idx = 0;
        float dv = 0.0f;
        if (lane < cc) {
            idx = csr_src[st + base + lane];
            dv = dinv[idx];
        }
        int j = 0;
        for (; j + 3 < cc; j += 4) {
            int s0 = __shfl(idx, j, 64);
            int s1 = __shfl(idx, j + 1, 64);
            int s2 = __shfl(idx, j + 2, 64);
            int s3 = __shfl(idx, j + 3, 64);
            float c0 = __shfl(dv, j, 64) * di;
            float c1 = __shfl(dv, j + 1, 64) * di;
            float c2 = __shfl(dv, j + 2, 64) * di;
            float c3 = __shfl(dv, j + 3, 64) * di;
            float2 v0 = hp2[(size_t)s0 * 64 + lane];
            float2 v1 = hp2[(size_t)s1 * 64 + lane];
            float2 v2 = hp2[(size_t)s2 * 64 + lane];
            float2 v3 = hp2[(size_t)s3 * 64 + lane];
            accx = fmaf(v0.x, c0, accx); accy = fmaf(v0.y, c0, accy);
            accx = fmaf(v1.x, c1, accx); accy = fmaf(v1.y, c1, accy);
            accx = fmaf(v2.x, c2, accx); accy = fmaf(v2.y, c2, accy);
            accx = fmaf(v3.x, c3, accx); accy = fmaf(v3.y, c3, accy);
        }
        for (; j < cc; j++) {
            int s = __shfl(idx, j, 64);
            float co = __shfl(dv, j, 64) * di;
            float2 v = hp2[(size_t)s * 64 + lane];
            accx = fmaf(v.x, co, accx); accy = fmaf(v.y, co, accy);
        }
    }
    float2 bb = ((const float2*)b)[lane];
    float2 o;
    o.x = fmaxf(accx + bb.x, 0.0f);
    o.y = fmaxf(accy + bb.y, 0.0f);
    ((float2*)ha)[(size_t)i * 64 + lane] = o;
    // fused attention score: cs[i] = sum_h (o_h . A_h) * (o_h . psW_h)
    float2 Av = ((const float2*)A)[lane];
    float2 Pv = ((const float2*)psW)[lane];
    float a = o.x * Av.x + o.y * Av.y;
    float p = o.x * Pv.x + o.y * Pv.y;
#pragma unroll
    for (int d = 8; d > 0; d >>= 1) {
        a += __shfl_down(a, d, 16);
        p += __shfl_down(p, d, 16);
    }
    float part = a * p;                  // heads at lanes 0,16,32,48
    part += __shfl_down(part, 16, 64);
    part += __shfl_down(part, 32, 64);
    if (lane == 0) cs[i] = part;
}

// ---------------------------------------------------------------------------
// Fused score-aggregation + per-graph top-k SET via 4-pass radix select with
// parallel digit selection (wave shfl suffix-scan over 256 bins).
// ---------------------------------------------------------------------------
__global__ void topk_kernel(const float* __restrict__ cs, const float* __restrict__ dinv,
                            const int* __restrict__ rowptr, const int* __restrict__ rowcnt,
                            const int* __restrict__ csr_src, const float* __restrict__ psb,
                            int nper, int k, int* __restrict__ nmap, int* __restrict__ perm,
                            float* __restrict__ mult) {
    __shared__ float sc[NPER0];
    __shared__ unsigned ukey[NPER0];
    __shared__ unsigned hist[256];
    __shared__ unsigned wtot[4];
    __shared__ unsigned sel[2];  // [0]=prefix/threshold, [1]=need (ties to keep)
    __shared__ int ctr[2];
    const int g = blockIdx.x, t = threadIdx.x;
    const int w = t >> 6, l = t & 63;
    const int gnb = g * nper;
    const float pb = psb[0];
    for (int i = t; i < nper; i += 256) {
        int node = gnb + i;
        float di = dinv[node];
        float acc = cs[node] * di * di;
        int st = rowptr[node], c = rowcnt[node];
        for (int j = 0; j < c; j++) {
            int s = csr_src[st + j];
            acc = fmaf(cs[s], dinv[s] * di, acc);
        }
        float v = acc + pb;
        sc[i] = v;
        ukey[i] = enc_f(v);
    }
    if (t == 0) { sel[0] = 0u; sel[1] = (unsigned)k; }
    __syncthreads();
    for (int shift = 24; shift >= 0; shift -= 8) {
        hist[t] = 0u;
        __syncthreads();
        const unsigned prefix = sel[0];
        const unsigned need = sel[1];
        for (int i = t; i < nper; i += 256) {
            unsigned u = ukey[i];
            if (shift == 24 || (u >> (shift + 8)) == (prefix >> (shift + 8)))
                atomicAdd(&hist[(u >> shift) & 255], 1u);
        }
        __syncthreads();
        const unsigned h = hist[t];
        unsigned s = h;
#pragma unroll
        for (int off = 1; off < 64; off <<= 1) {
            unsigned v = __shfl_down(s, off, 64);
            if (l + off < 64) s += v;
        }
        if (l == 0) wtot[w] = s;
        __syncthreads();
        unsigned add = 0;
        for (int ww = w + 1; ww < 4; ww++) add += wtot[ww];
        const unsigned sfx = s + add;
        const unsigned gtr = sfx - h;
        if (sfx >= need && gtr < need) {  // exactly one thread
            sel[0] = prefix | ((unsigned)t << shift);
            sel[1] = need - gtr;
        }
        __syncthreads();
    }
    const unsigned T = sel[0];
    const int need = (int)sel[1];
    if (t == 0) { ctr[0] = 0; ctr[1] = k - need; }
    __syncthreads();
    for (int i = t; i < nper; i += 256) {
        unsigned u = ukey[i];
        int node = gnb + i;
        int newid = -1;
        if (u > T) {
            newid = g * k + atomicAdd(&ctr[0], 1);
        } else if (u == T) {
            int slot = atomicAdd(&ctr[1], 1);
            if (slot < k) newid = g * k + slot;
        }
        nmap[node] = newid;
        if (newid >= 0) {
            perm[newid] = node;
            mult[newid] = tanhf(sc[i]);
        }
    }
}

// ---------------------------------------------------------------------------
// Fat kernel: edge remap + next-stage degree count (blocks < rb) | pooling
// gather with atomic readout (rest). Both depend only on topk.
// poolgather: 8 kept nodes/block, 256 threads = (feature, node-half);
// readout via atomicMax(enc)/atomicAdd into rmax/rsum.
// ---------------------------------------------------------------------------
__global__ void pg_remap(const float* __restrict__ ha, const int* __restrict__ perm,
                         const float* __restrict__ mult, int k,
                         float* __restrict__ xn,
                         unsigned* __restrict__ rmax, float* __restrict__ rsum,
                         int rb,
                         const int* __restrict__ src, const int* __restrict__ dst,
                         const int* __restrict__ nmap,
                         int* __restrict__ nsrc, int* __restrict__ ndst,
                         int* __restrict__ cnt_next) {
    __shared__ float smax[128], ssum[128];
    const int t = threadIdx.x;
    if (blockIdx.x < rb) {
        int e = blockIdx.x * 256 + t;
        int so = src[e];
        int ns = (so >= 0) ? nmap[so] : -1;
        int nd = nmap[dst[e]];
        bool valid = (ns >= 0) && (nd >= 0);
        nsrc[e] = valid ? ns : -1;
        ndst[e] = valid ? nd : 0;
        if (valid) atomicAdd(&cnt_next[nd], 1);
        return;
    }
    const int pb = blockIdx.x - rb;
    const int g = pb & 31;
    const int c = pb >> 5;
    const int f = t & 127, half = t >> 7;
    const int base = g * k + c * 8;
    float vmax = -1e30f, vsum = 0.0f;
#pragma unroll
    for (int j0 = 0; j0 < 4; j0++) {
        int newid = base + half + j0 * 2;
        int old = perm[newid];
        float m = mult[newid];
        float v = ha[(size_t)old * FDIM + f] * m;
        xn[(size_t)newid * FDIM + f] = v;
        vmax = fmaxf(vmax, v);
        vsum += v;
    }
    if (half) { smax[f] = vmax; ssum[f] = vsum; }
    __syncthreads();
    if (!half) {
        vmax = fmaxf(vmax, smax[f]);
        vsum += ssum[f];
        atomicMax(&rmax[g * FDIM + f], enc_f(vmax));
        atomicAdd(&rsum[g * FDIM + f], vsum);
    }
}

// ---------------------------------------------------------------------------
// Final MLP + log_softmax. One block per graph, 128 threads. Decodes the
// atomic readout accumulators (3 stages).
// ---------------------------------------------------------------------------
__global__ void final_mlp(const unsigned* __restrict__ rmax, const float* __restrict__ rsum,
                          const float* __restrict__ l1W, const float* __restrict__ l1b,
                          const float* __restrict__ l2W, const float* __restrict__ l2b,
                          const float* __restrict__ l3W, const float* __restrict__ l3b,
                          float* __restrict__ out) {
    __shared__ float sz[256], s1[128], s2[64], s3[10], red[2];
    const int g = blockIdx.x, t = threadIdx.x;
    const int RS = BGR * FDIM;
    sz[t] = dec_f(rmax[g * FDIM + t]) + dec_f(rmax[RS + g * FDIM + t]) +
            dec_f(rmax[2 * RS + g * FDIM + t]);
    sz[t + 128] = rsum[g * FDIM + t] / (float)K1 + rsum[RS + g * FDIM + t] / (float)K2 +
                  rsum[2 * RS + g * FDIM + t] / (float)K3;
    __syncthreads();
    float acc = l1b[t];
    for (int i = 0; i < 256; i++) acc = fmaf(sz[i], l1W[i * 128 + t], acc);
    s1[t] = fmaxf(acc, 0.0f);
    __syncthreads();
    if (t < 64) {
        float a2 = l2b[t];
        for (int i = 0; i < 128; i++) a2 = fmaf(s1[i], l2W[i * 64 + t], a2);
        s2[t] = fmaxf(a2, 0.0f);
    }
    __syncthreads();
    if (t < 10) {
        float a3 = l3b[t];
        for (int i = 0; i < 64; i++) a3 = fmaf(s2[i], l3W[i * 10 + t], a3);
        s3[t] = a3;
    }
    __syncthreads();
    if (t == 0) {
        float m = -1e30f;
        for (int c = 0; c < 10; c++) m = fmaxf(m, s3[c]);
        float sum = 0.0f;
        for (int c = 0; c < 10; c++) sum += expf(s3[c] - m);
        red[0] = m;
        red[1] = logf(sum);
    }
    __syncthreads();
    if (t < 10) out[g * 10 + t] = s3[t] - red[0] - red[1];
}

// ---------------------------------------------------------------------------
extern "C" void kernel_launch(void* const* d_in, const int* in_sizes, int n_in,
                              void* d_out, int out_size, void* d_ws, size_t ws_size,
                              hipStream_t stream) {
    const float* x    = (const float*)d_in[0];
    const int* src0   = (const int*)d_in[1];
    const int* dst0   = (const int*)d_in[2];
    const float* W1   = (const float*)d_in[3];
    const float* b1   = (const float*)d_in[4];
    const float* A1   = (const float*)d_in[5];
    const float* ps1W = (const float*)d_in[6];
    const float* ps1b = (const float*)d_in[7];
    const float* W2   = (const float*)d_in[8];
    const float* b2   = (const float*)d_in[9];
    const float* A2   = (const float*)d_in[10];
    const float* ps2W = (const float*)d_in[11];
    const float* ps2b = (const float*)d_in[12];
    const float* W3   = (const float*)d_in[13];
    const float* b3   = (const float*)d_in[14];
    const float* A3   = (const float*)d_in[15];
    const float* ps3W = (const float*)d_in[16];
    const float* ps3b = (const float*)d_in[17];
    const float* l1W  = (const float*)d_in[18];
    const float* l1b  = (const float*)d_in[19];
    const float* l2W  = (const float*)d_in[20];
    const float* l2b  = (const float*)d_in[21];
    const float* l3W  = (const float*)d_in[22];
    const float* l3b  = (const float*)d_in[23];
    float* out = (float*)d_out;

    char* ws = (char*)d_ws;
    size_t o = 0;
    auto alloc = [&](size_t bytes) -> void* {
        void* p = ws + o;
        o += (bytes + 255) & ~(size_t)255;
        return p;
    };
    float*    hproj = (float*)alloc((size_t)N0 * FDIM * 4);
    float*    hact  = (float*)alloc((size_t)N0 * FDIM * 4);
    float*    xn    = (float*)alloc((size_t)N0 * FDIM * 4);
    int*      cntA  = (int*)alloc(N0 * 4);
    int*      cntB  = (int*)alloc(BGR * K1 * 4);
    int*      cntC  = (int*)alloc(BGR * K2 * 4);
    float*    dinv  = (float*)alloc(N0 * 4);
    int*      rowptr= (int*)alloc(N0 * 4);
    int*      rowcnt= (int*)alloc(N0 * 4);
    int*      csr   = (int*)alloc(EDG * 4);
    float*    cs    = (float*)alloc(N0 * 4);
    int*      nmap  = (int*)alloc(N0 * 4);
    int*      perm  = (int*)alloc(BGR * K1 * 4);
    float*    mult  = (float*)alloc(BGR * K1 * 4);
    unsigned* rmax  = (unsigned*)alloc(3 * BGR * FDIM * 4);
    float*    rsum  = (float*)alloc(3 * BGR * FDIM * 4);
    int*      se1   = (int*)alloc(EDG * 4);
    int*      de1   = (int*)alloc(EDG * 4);
    int*      se2   = (int*)alloc(EDG * 4);
    int*      de2   = (int*)alloc(EDG * 4);

    const int n1 = BGR * K1, n2 = BGR * K2;

    // ---------------- Stage 1: n=32768, nper=1024, k=512 ----------------
    zero_all<<<N0 / 256, 256, 0, stream>>>(cntA, rmax, rsum);
    count_proj<<<EBLK + N0 / 32, 256, 0, stream>>>(src0, dst0, cntA, x, W1, hproj);
    scan_kernel<<<BGR, 256, 0, stream>>>(cntA, NPER0, dinv, rowptr, rowcnt, cntB, n1);
    scatter_proj<<<EBLK, 256, 0, stream>>>(src0, dst0, rowptr, cntA, csr,
                                           nullptr, nullptr, nullptr);
    agg_kernel<<<N0 / 4, 256, 0, stream>>>(hproj, b1, dinv, rowptr, rowcnt, csr,
                                           A1, ps1W, hact, cs, NPER0);
    topk_kernel<<<BGR, 256, 0, stream>>>(cs, dinv, rowptr, rowcnt, csr, ps1b,
                                         NPER0, K1, nmap, perm, mult);
    pg_remap<<<EBLK + BGR * K1 / 8, 256, 0, stream>>>(hact, perm, mult, K1, xn,
                                                      rmax, rsum, EBLK,
                                                      src0, dst0, nmap, se1, de1, cntB);

    // ---------------- Stage 2: n=16384, nper=512, k=256 ----------------
    scan_kernel<<<BGR, 256, 0, stream>>>(cntB, K1, dinv, rowptr, rowcnt, cntC, n2);
    scatter_proj<<<EBLK + n1 / 32, 256, 0, stream>>>(se1, de1, rowptr, cntB, csr,
                                                     xn, W2, hproj);
    agg_kernel<<<n1 / 4, 256, 0, stream>>>(hproj, b2, dinv, rowptr, rowcnt, csr,
                                           A2, ps2W, hact, cs, K1);
    topk_kernel<<<BGR, 256, 0, stream>>>(cs, dinv, rowptr, rowcnt, csr, ps2b,
                                         K1, K2, nmap, perm, mult);
    pg_remap<<<EBLK + BGR * K2 / 8, 256, 0, stream>>>(hact, perm, mult, K2, xn,
                                                      rmax + BGR * FDIM, rsum + BGR * FDIM,
                                                      EBLK,
                                                      se1, de1, nmap, se2, de2, cntC);

    // ---------------- Stage 3: n=8192, nper=256, k=128 ----------------
    scan_kernel<<<BGR, 256, 0, stream>>>(cntC, K2, dinv, rowptr, rowcnt, nullptr, 0);
    scatter_proj<<<EBLK + n2 / 32, 256, 0, stream>>>(se2, de2, rowptr, cntC, csr,
                                                     xn, W3, hproj);
    agg_kernel<<<n2 / 4, 256, 0, stream>>>(hproj, b3, dinv, rowptr, rowcnt, csr,
                                           A3, ps3W, hact, cs, K2);
    topk_kernel<<<BGR, 256, 0, stream>>>(cs, dinv, rowptr, rowcnt, csr, ps3b,
                                         K2, K3, nmap, perm, mult);
    pg_remap<<<BGR * K3 / 8, 256, 0, stream>>>(hact, perm, mult, K3, xn,
                                               rmax + 2 * BGR * FDIM, rsum + 2 * BGR * FDIM,
                                               0,
                                               nullptr, nullptr, nullptr, nullptr, nullptr,
                                               nullptr);

    // ---------------- Final MLP ----------------
    final_mlp<<<BGR, 128, 0, stream>>>(rmax, rsum, l1W, l1b, l2W, l2b, l3W, l3b, out);

    (void)in_sizes; (void)n_in; (void)out_size; (void)ws_size;
}

// Round 8
// 318.774 us; speedup vs baseline: 1.7336x; 1.1865x over previous
//
#include <hip/hip_runtime.h>
#include <math.h>

#define BGR 32
#define NPER0 1024
#define N0 (BGR * NPER0)
#define FDIM 128
#define EDG 524288
#define EPG (EDG / BGR)
#define K1 512
#define K2 256
#define K3 128
#define EBLK (EDG / 256)  // edge-parallel blocks (2048)
#define SXP 36            // sxT row pad (floats): keeps b128 16B-aligned, banks spread

// Order-preserving float<->uint encoding (for atomicMax on floats).
__device__ __forceinline__ unsigned enc_f(float v) {
    unsigned u = __float_as_uint(v);
    return (u & 0x80000000u) ? ~u : (u | 0x80000000u);
}
__device__ __forceinline__ float dec_f(unsigned u) {
    return (u & 0x80000000u) ? __uint_as_float(u ^ 0x80000000u) : __uint_as_float(~u);
}

// ---------------------------------------------------------------------------
// Register-tiled per-head projection body: 32 nodes x 128 features per block.
// Thread = (feature-quad fg = t>>3, node-quad ng = t&7); 4x4 outer product,
// 2 x ds_read_b128 per k-step (vs 32 x ds_read_b32 scalar: LDS pipe was the
// bottleneck at ~3000 cyc/wave). h = fg>>3 = wave id.
// ---------------------------------------------------------------------------
__device__ __forceinline__ void proj_body(const float* __restrict__ x,
                                          const float* __restrict__ W,
                                          float* __restrict__ hp, int nb, int t,
                                          float* __restrict__ sW,
                                          float* __restrict__ sxT) {
    for (int i = t; i < 4096; i += 256) sW[i] = W[i];
    for (int i = t; i < 4096; i += 256) {
        int node = i >> 7, dim = i & 127;
        sxT[dim * SXP + node] = x[(size_t)(nb + node) * FDIM + dim];
    }
    __syncthreads();
    const int fg = t >> 3;      // 0..31  (features fg*4 .. fg*4+3)
    const int ng = t & 7;       // 0..7   (nodes ng*4 .. ng*4+3)
    const int h = fg >> 3;
    const float* ap = sxT + h * 32 * SXP + ng * 4;
    const float* bp = sW + h * 1024 + (fg & 7) * 4;
    float4 acc0 = {0.f, 0.f, 0.f, 0.f}, acc1 = acc0, acc2 = acc0, acc3 = acc0;
#pragma unroll
    for (int k = 0; k < 32; k++) {
        float4 a = *(const float4*)(ap + k * SXP);
        float4 b = *(const float4*)(bp + k * 32);
        acc0.x = fmaf(a.x, b.x, acc0.x); acc0.y = fmaf(a.x, b.y, acc0.y);
        acc0.z = fmaf(a.x, b.z, acc0.z); acc0.w = fmaf(a.x, b.w, acc0.w);
        acc1.x = fmaf(a.y, b.x, acc1.x); acc1.y = fmaf(a.y, b.y, acc1.y);
        acc1.z = fmaf(a.y, b.z, acc1.z); acc1.w = fmaf(a.y, b.w, acc1.w);
        acc2.x = fmaf(a.z, b.x, acc2.x); acc2.y = fmaf(a.z, b.y, acc2.y);
        acc2.z = fmaf(a.z, b.z, acc2.z); acc2.w = fmaf(a.z, b.w, acc2.w);
        acc3.x = fmaf(a.w, b.x, acc3.x); acc3.y = fmaf(a.w, b.y, acc3.y);
        acc3.z = fmaf(a.w, b.z, acc3.z); acc3.w = fmaf(a.w, b.w, acc3.w);
    }
    float4* op = (float4*)(hp + (size_t)(nb + ng * 4) * FDIM + fg * 4);
    op[0]  = acc0;          // node stride = FDIM floats = 32 float4
    op[32] = acc1;
    op[64] = acc2;
    op[96] = acc3;
}

// ---------------------------------------------------------------------------
// Per-call zero of stage-1 degree counters + all readout accumulators.
// ---------------------------------------------------------------------------
__global__ void zero_all(int* __restrict__ cntA, unsigned* __restrict__ rmax,
                         float* __restrict__ rsum) {
    int i = blockIdx.x * 256 + threadIdx.x;
    if (i < N0) cntA[i] = 0;
    if (i < 3 * BGR * FDIM) { rmax[i] = 0u; rsum[i] = 0.0f; }
}

// ---------------------------------------------------------------------------
// Fat kernel: edge-degree count (blocks < EBLK) | projection (rest).
// ---------------------------------------------------------------------------
__global__ void count_proj(const int* __restrict__ src, const int* __restrict__ dst,
                           int* __restrict__ cnt,
                           const float* __restrict__ x, const float* __restrict__ W,
                           float* __restrict__ hp) {
    __shared__ __align__(16) float sW[4096];
    __shared__ __align__(16) float sxT[128 * SXP];
    const int t = threadIdx.x;
    if (blockIdx.x < EBLK) {
        int e = blockIdx.x * 256 + t;
        int s = src[e];
        if (s >= 0) atomicAdd(&cnt[dst[e]], 1);
        return;
    }
    proj_body(x, W, hp, (blockIdx.x - EBLK) * 32, t, sW, sxT);
}

// ---------------------------------------------------------------------------
// Fat kernel: CSR scatter (blocks < EBLK) | projection (rest). Stages 2/3.
// ---------------------------------------------------------------------------
__global__ void scatter_proj(const int* __restrict__ src, const int* __restrict__ dst,
                             const int* __restrict__ rowptr, int* __restrict__ cursor,
                             int* __restrict__ csr_src,
                             const float* __restrict__ x, const float* __restrict__ W,
                             float* __restrict__ hp) {
    __shared__ __align__(16) float sW[4096];
    __shared__ __align__(16) float sxT[128 * SXP];
    const int t = threadIdx.x;
    if (blockIdx.x < EBLK) {
        int e = blockIdx.x * 256 + t;
        int s = src[e];
        if (s >= 0) {
            int d = dst[e];
            int p = atomicAdd(&cursor[d], 1);
            csr_src[rowptr[d] + p] = s;
        }
        return;
    }
    proj_body(x, W, hp, (blockIdx.x - EBLK) * 32, t, sW, sxT);
}

// ---------------------------------------------------------------------------
// Per-graph exclusive scan of cnt -> rowptr; writes dinv/rowcnt; zeroes cnt
// (reused as scatter cursor) and the NEXT stage's cnt buffer.
// ---------------------------------------------------------------------------
__global__ void scan_kernel(int* __restrict__ cnt, int nper,
                            float* __restrict__ dinv,
                            int* __restrict__ rowptr, int* __restrict__ rowcnt,
                            int* __restrict__ cnt_next, int n_next) {
    __shared__ int scnt[NPER0];
    __shared__ int soff[NPER0];
    __shared__ int psum[256];
    const int g = blockIdx.x, t = threadIdx.x;
    const int gnb = g * nper, ebase = g * EPG;
    for (int i = blockIdx.x * 256 + t; i < n_next; i += BGR * 256) cnt_next[i] = 0;
    for (int i = t; i < nper; i += 256) scnt[i] = cnt[gnb + i];
    __syncthreads();
    const int S = nper >> 8;  // 4, 2, or 1
    const int b0 = t * S;
    int loc = 0;
    for (int q = 0; q < S; q++) loc += scnt[b0 + q];
    psum[t] = loc;
    __syncthreads();
    if (t == 0) {
        int run = 0;
        for (int i = 0; i < 256; i++) { int v = psum[i]; psum[i] = run; run += v; }
    }
    __syncthreads();
    int run = psum[t];
    for (int q = 0; q < S; q++) { soff[b0 + q] = run; run += scnt[b0 + q]; }
    __syncthreads();
    for (int i = t; i < nper; i += 256) {
        int c = scnt[i];
        dinv[gnb + i] = rsqrtf((float)c + 1.0f);
        rowptr[gnb + i] = ebase + soff[i];
        rowcnt[gnb + i] = c;
        cnt[gnb + i] = 0;  // cursor for scatter
    }
}

// ---------------------------------------------------------------------------
// GCN aggregation (gather via CSR) + bias + relu, FUSED with the attention
// score projection. One WAVE per node; lane covers 2 features (float2);
// shfl-broadcast edge prefetch (4x unrolled). Graph->XCD swizzle: blk%32.
// ---------------------------------------------------------------------------
__global__ void agg_kernel(const float* __restrict__ hp, const float* __restrict__ b,
                           const float* __restrict__ dinv, const int* __restrict__ rowptr,
                           const int* __restrict__ rowcnt, const int* __restrict__ csr_src,
                           const float* __restrict__ A, const float* __restrict__ psW,
                           float* __restrict__ ha, float* __restrict__ cs, int nper) {
    const int w = threadIdx.x >> 6;
    const int lane = threadIdx.x & 63;
    const int g = blockIdx.x & 31;
    const int chunk = blockIdx.x >> 5;
    const int i = g * nper + chunk * 4 + w;
    const float di = dinv[i];
    const float2* __restrict__ hp2 = (const float2*)hp;
    float2 self = hp2[(size_t)i * 64 + lane];
    float accx = self.x * di * di, accy = self.y * di * di;
    const int st = rowptr[i];
    const int c = rowcnt[i];
    for (int base = 0; base < c; base += 64) {
        const int cc = min(64, c - base);
        int idx = 0;
        float dv = 0.0f;
        if (lane < cc) {
            idx = csr_src[st + base + lane];
            dv = dinv[idx];
        }
        int j = 0;
        for (; j + 3 < cc; j += 4) {
            int s0 = __shfl(idx, j, 64);
            int s1 = __shfl(idx, j + 1, 64);
            int s2 = __shfl(idx, j + 2, 64);
            int s3 = __shfl(idx, j + 3, 64);
            float c0 = __shfl(dv, j, 64) * di;
            float c1 = __shfl(dv, j + 1, 64) * di;
            float c2 = __shfl(dv, j + 2, 64) * di;
            float c3 = __shfl(dv, j + 3, 64) * di;
            float2 v0 = hp2[(size_t)s0 * 64 + lane];
            float2 v1 = hp2[(size_t)s1 * 64 + lane];
            float2 v2 = hp2[(size_t)s2 * 64 + lane];
            float2 v3 = hp2[(size_t)s3 * 64 + lane];
            accx = fmaf(v0.x, c0, accx); accy = fmaf(v0.y, c0, accy);
            accx = fmaf(v1.x, c1, accx); accy = fmaf(v1.y, c1, accy);
            accx = fmaf(v2.x, c2, accx); accy = fmaf(v2.y, c2, accy);
            accx = fmaf(v3.x, c3, accx); accy = fmaf(v3.y, c3, accy);
        }
        for (; j < cc; j++) {
            int s = __shfl(idx, j, 64);
            float co = __shfl(dv, j, 64) * di;
            float2 v = hp2[(size_t)s * 64 + lane];
            accx = fmaf(v.x, co, accx); accy = fmaf(v.y, co, accy);
        }
    }
    float2 bb = ((const float2*)b)[lane];
    float2 o;
    o.x = fmaxf(accx + bb.x, 0.0f);
    o.y = fmaxf(accy + bb.y, 0.0f);
    ((float2*)ha)[(size_t)i * 64 + lane] = o;
    // fused attention score: cs[i] = sum_h (o_h . A_h) * (o_h . psW_h)
    float2 Av = ((const float2*)A)[lane];
    float2 Pv = ((const float2*)psW)[lane];
    float a = o.x * Av.x + o.y * Av.y;
    float p = o.x * Pv.x + o.y * Pv.y;
#pragma unroll
    for (int d = 8; d > 0; d >>= 1) {
        a += __shfl_down(a, d, 16);
        p += __shfl_down(p, d, 16);
    }
    float part = a * p;                  // heads at lanes 0,16,32,48
    part += __shfl_down(part, 16, 64);
    part += __shfl_down(part, 32, 64);
    if (lane == 0) cs[i] = part;
}

// ---------------------------------------------------------------------------
// Fused score-aggregation + per-graph top-k SET via 4-pass radix select with
// parallel digit selection (wave shfl suffix-scan over 256 bins).
// ---------------------------------------------------------------------------
__global__ void topk_kernel(const float* __restrict__ cs, const float* __restrict__ dinv,
                            const int* __restrict__ rowptr, const int* __restrict__ rowcnt,
                            const int* __restrict__ csr_src, const float* __restrict__ psb,
                            int nper, int k, int* __restrict__ nmap, int* __restrict__ perm,
                            float* __restrict__ mult) {
    __shared__ float sc[NPER0];
    __shared__ unsigned ukey[NPER0];
    __shared__ unsigned hist[256];
    __shared__ unsigned wtot[4];
    __shared__ unsigned sel[2];  // [0]=prefix/threshold, [1]=need (ties to keep)
    __shared__ int ctr[2];
    const int g = blockIdx.x, t = threadIdx.x;
    const int w = t >> 6, l = t & 63;
    const int gnb = g * nper;
    const float pb = psb[0];
    for (int i = t; i < nper; i += 256) {
        int node = gnb + i;
        float di = dinv[node];
        float acc = cs[node] * di * di;
        int st = rowptr[node], c = rowcnt[node];
        for (int j = 0; j < c; j++) {
            int s = csr_src[st + j];
            acc = fmaf(cs[s], dinv[s] * di, acc);
        }
        float v = acc + pb;
        sc[i] = v;
        ukey[i] = enc_f(v);
    }
    if (t == 0) { sel[0] = 0u; sel[1] = (unsigned)k; }
    __syncthreads();
    for (int shift = 24; shift >= 0; shift -= 8) {
        hist[t] = 0u;
        __syncthreads();
        const unsigned prefix = sel[0];
        const unsigned need = sel[1];
        for (int i = t; i < nper; i += 256) {
            unsigned u = ukey[i];
            if (shift == 24 || (u >> (shift + 8)) == (prefix >> (shift + 8)))
                atomicAdd(&hist[(u >> shift) & 255], 1u);
        }
        __syncthreads();
        const unsigned h = hist[t];
        unsigned s = h;
#pragma unroll
        for (int off = 1; off < 64; off <<= 1) {
            unsigned v = __shfl_down(s, off, 64);
            if (l + off < 64) s += v;
        }
        if (l == 0) wtot[w] = s;
        __syncthreads();
        unsigned add = 0;
        for (int ww = w + 1; ww < 4; ww++) add += wtot[ww];
        const unsigned sfx = s + add;
        const unsigned gtr = sfx - h;
        if (sfx >= need && gtr < need) {  // exactly one thread
            sel[0] = prefix | ((unsigned)t << shift);
            sel[1] = need - gtr;
        }
        __syncthreads();
    }
    const unsigned T = sel[0];
    const int need = (int)sel[1];
    if (t == 0) { ctr[0] = 0; ctr[1] = k - need; }
    __syncthreads();
    for (int i = t; i < nper; i += 256) {
        unsigned u = ukey[i];
        int node = gnb + i;
        int newid = -1;
        if (u > T) {
            newid = g * k + atomicAdd(&ctr[0], 1);
        } else if (u == T) {
            int slot = atomicAdd(&ctr[1], 1);
            if (slot < k) newid = g * k + slot;
        }
        nmap[node] = newid;
        if (newid >= 0) {
            perm[newid] = node;
            mult[newid] = tanhf(sc[i]);
        }
    }
}

// ---------------------------------------------------------------------------
// Fat kernel: edge remap + next-stage degree count (blocks < rb) | pooling
// gather with atomic readout (rest).
// ---------------------------------------------------------------------------
__global__ void pg_remap(const float* __restrict__ ha, const int* __restrict__ perm,
                         const float* __restrict__ mult, int k,
                         float* __restrict__ xn,
                         unsigned* __restrict__ rmax, float* __restrict__ rsum,
                         int rb,
                         const int* __restrict__ src, const int* __restrict__ dst,
                         const int* __restrict__ nmap,
                         int* __restrict__ nsrc, int* __restrict__ ndst,
                         int* __restrict__ cnt_next) {
    __shared__ float smax[128], ssum[128];
    const int t = threadIdx.x;
    if (blockIdx.x < rb) {
        int e = blockIdx.x * 256 + t;
        int so = src[e];
        int ns = (so >= 0) ? nmap[so] : -1;
        int nd = nmap[dst[e]];
        bool valid = (ns >= 0) && (nd >= 0);
        nsrc[e] = valid ? ns : -1;
        ndst[e] = valid ? nd : 0;
        if (valid) atomicAdd(&cnt_next[nd], 1);
        return;
    }
    const int pb = blockIdx.x - rb;
    const int g = pb & 31;
    const int c = pb >> 5;
    const int f = t & 127, half = t >> 7;
    const int base = g * k + c * 8;
    float vmax = -1e30f, vsum = 0.0f;
#pragma unroll
    for (int j0 = 0; j0 < 4; j0++) {
        int newid = base + half + j0 * 2;
        int old = perm[newid];
        float m = mult[newid];
        float v = ha[(size_t)old * FDIM + f] * m;
        xn[(size_t)newid * FDIM + f] = v;
        vmax = fmaxf(vmax, v);
        vsum += v;
    }
    if (half) { smax[f] = vmax; ssum[f] = vsum; }
    __syncthreads();
    if (!half) {
        vmax = fmaxf(vmax, smax[f]);
        vsum += ssum[f];
        atomicMax(&rmax[g * FDIM + f], enc_f(vmax));
        atomicAdd(&rsum[g * FDIM + f], vsum);
    }
}

// ---------------------------------------------------------------------------
// Final MLP + log_softmax. One block per graph, 128 threads.
// ---------------------------------------------------------------------------
__global__ void final_mlp(const unsigned* __restrict__ rmax, const float* __restrict__ rsum,
                          const float* __restrict__ l1W, const float* __restrict__ l1b,
                          const float* __restrict__ l2W, const float* __restrict__ l2b,
                          const float* __restrict__ l3W, const float* __restrict__ l3b,
                          float* __restrict__ out) {
    __shared__ float sz[256], s1[128], s2[64], s3[10], red[2];
    const int g = blockIdx.x, t = threadIdx.x;
    const int RS = BGR * FDIM;
    sz[t] = dec_f(rmax[g * FDIM + t]) + dec_f(rmax[RS + g * FDIM + t]) +
            dec_f(rmax[2 * RS + g * FDIM + t]);
    sz[t + 128] = rsum[g * FDIM + t] / (float)K1 + rsum[RS + g * FDIM + t] / (float)K2 +
                  rsum[2 * RS + g * FDIM + t] / (float)K3;
    __syncthreads();
    float acc = l1b[t];
    for (int i = 0; i < 256; i++) acc = fmaf(sz[i], l1W[i * 128 + t], acc);
    s1[t] = fmaxf(acc, 0.0f);
    __syncthreads();
    if (t < 64) {
        float a2 = l2b[t];
        for (int i = 0; i < 128; i++) a2 = fmaf(s1[i], l2W[i * 64 + t], a2);
        s2[t] = fmaxf(a2, 0.0f);
    }
    __syncthreads();
    if (t < 10) {
        float a3 = l3b[t];
        for (int i = 0; i < 64; i++) a3 = fmaf(s2[i], l3W[i * 10 + t], a3);
        s3[t] = a3;
    }
    __syncthreads();
    if (t == 0) {
        float m = -1e30f;
        for (int c = 0; c < 10; c++) m = fmaxf(m, s3[c]);
        float sum = 0.0f;
        for (int c = 0; c < 10; c++) sum += expf(s3[c] - m);
        red[0] = m;
        red[1] = logf(sum);
    }
    __syncthreads();
    if (t < 10) out[g * 10 + t] = s3[t] - red[0] - red[1];
}

// ---------------------------------------------------------------------------
extern "C" void kernel_launch(void* const* d_in, const int* in_sizes, int n_in,
                              void* d_out, int out_size, void* d_ws, size_t ws_size,
                              hipStream_t stream) {
    const float* x    = (const float*)d_in[0];
    const int* src0   = (const int*)d_in[1];
    const int* dst0   = (const int*)d_in[2];
    const float* W1   = (const float*)d_in[3];
    const float* b1   = (const float*)d_in[4];
    const float* A1   = (const float*)d_in[5];
    const float* ps1W = (const float*)d_in[6];
    const float* ps1b = (const float*)d_in[7];
    const float* W2   = (const float*)d_in[8];
    const float* b2   = (const float*)d_in[9];
    const float* A2   = (const float*)d_in[10];
    const float* ps2W = (const float*)d_in[11];
    const float* ps2b = (const float*)d_in[12];
    const float* W3   = (const float*)d_in[13];
    const float* b3   = (const float*)d_in[14];
    const float* A3   = (const float*)d_in[15];
    const float* ps3W = (const float*)d_in[16];
    const float* ps3b = (const float*)d_in[17];
    const float* l1W  = (const float*)d_in[18];
    const float* l1b  = (const float*)d_in[19];
    const float* l2W  = (const float*)d_in[20];
    const float* l2b  = (const float*)d_in[21];
    const float* l3W  = (const float*)d_in[22];
    const float* l3b  = (const float*)d_in[23];
    float* out = (float*)d_out;

    char* ws = (char*)d_ws;
    size_t o = 0;
    auto alloc = [&](size_t bytes) -> void* {
        void* p = ws + o;
        o += (bytes + 255) & ~(size_t)255;
        return p;
    };
    float*    hproj = (float*)alloc((size_t)N0 * FDIM * 4);
    float*    hact  = (float*)alloc((size_t)N0 * FDIM * 4);
    float*    xn    = (float*)alloc((size_t)N0 * FDIM * 4);
    int*      cntA  = (int*)alloc(N0 * 4);
    int*      cntB  = (int*)alloc(BGR * K1 * 4);
    int*      cntC  = (int*)alloc(BGR * K2 * 4);
    float*    dinv  = (float*)alloc(N0 * 4);
    int*      rowptr= (int*)alloc(N0 * 4);
    int*      rowcnt= (int*)alloc(N0 * 4);
    int*      csr   = (int*)alloc(EDG * 4);
    float*    cs    = (float*)alloc(N0 * 4);
    int*      nmap  = (int*)alloc(N0 * 4);
    int*      perm  = (int*)alloc(BGR * K1 * 4);
    float*    mult  = (float*)alloc(BGR * K1 * 4);
    unsigned* rmax  = (unsigned*)alloc(3 * BGR * FDIM * 4);
    float*    rsum  = (float*)alloc(3 * BGR * FDIM * 4);
    int*      se1   = (int*)alloc(EDG * 4);
    int*      de1   = (int*)alloc(EDG * 4);
    int*      se2   = (int*)alloc(EDG * 4);
    int*      de2   = (int*)alloc(EDG * 4);

    const int n1 = BGR * K1, n2 = BGR * K2;

    // ---------------- Stage 1: n=32768, nper=1024, k=512 ----------------
    zero_all<<<N0 / 256, 256, 0, stream>>>(cntA, rmax, rsum);
    count_proj<<<EBLK + N0 / 32, 256, 0, stream>>>(src0, dst0, cntA, x, W1, hproj);
    scan_kernel<<<BGR, 256, 0, stream>>>(cntA, NPER0, dinv, rowptr, rowcnt, cntB, n1);
    scatter_proj<<<EBLK, 256, 0, stream>>>(src0, dst0, rowptr, cntA, csr,
                                           nullptr, nullptr, nullptr);
    agg_kernel<<<N0 / 4, 256, 0, stream>>>(hproj, b1, dinv, rowptr, rowcnt, csr,
                                           A1, ps1W, hact, cs, NPER0);
    topk_kernel<<<BGR, 256, 0, stream>>>(cs, dinv, rowptr, rowcnt, csr, ps1b,
                                         NPER0, K1, nmap, perm, mult);
    pg_remap<<<EBLK + BGR * K1 / 8, 256, 0, stream>>>(hact, perm, mult, K1, xn,
                                                      rmax, rsum, EBLK,
                                                      src0, dst0, nmap, se1, de1, cntB);

    // ---------------- Stage 2: n=16384, nper=512, k=256 ----------------
    scan_kernel<<<BGR, 256, 0, stream>>>(cntB, K1, dinv, rowptr, rowcnt, cntC, n2);
    scatter_proj<<<EBLK + n1 / 32, 256, 0, stream>>>(se1, de1, rowptr, cntB, csr,
                                                     xn, W2, hproj);
    agg_kernel<<<n1 / 4, 256, 0, stream>>>(hproj, b2, dinv, rowptr, rowcnt, csr,
                                           A2, ps2W, hact, cs, K1);
    topk_kernel<<<BGR, 256, 0, stream>>>(cs, dinv, rowptr, rowcnt, csr, ps2b,
                                         K1, K2, nmap, perm, mult);
    pg_remap<<<EBLK + BGR * K2 / 8, 256, 0, stream>>>(hact, perm, mult, K2, xn,
                                                      rmax + BGR * FDIM, rsum + BGR * FDIM,
                                                      EBLK,
                                                      se1, de1, nmap, se2, de2, cntC);

    // ---------------- Stage 3: n=8192, nper=256, k=128 ----------------
    scan_kernel<<<BGR, 256, 0, stream>>>(cntC, K2, dinv, rowptr, rowcnt, nullptr, 0);
    scatter_proj<<<EBLK + n2 / 32, 256, 0, stream>>>(se2, de2, rowptr, cntC, csr,
                                                     xn, W3, hproj);
    agg_kernel<<<n2 / 4, 256, 0, stream>>>(hproj, b3, dinv, rowptr, rowcnt, csr,
                                           A3, ps3W, hact, cs, K2);
    topk_kernel<<<BGR, 256, 0, stream>>>(cs, dinv, rowptr, rowcnt, csr, ps3b,
                                         K2, K3, nmap, perm, mult);
    pg_remap<<<BGR * K3 / 8, 256, 0, stream>>>(hact, perm, mult, K3, xn,
                                               rmax + 2 * BGR * FDIM, rsum + 2 * BGR * FDIM,
                                               0,
                                               nullptr, nullptr, nullptr, nullptr, nullptr,
                                               nullptr);

    // ---------------- Final MLP ----------------
    final_mlp<<<BGR, 128, 0, stream>>>(rmax, rsum, l1W, l1b, l2W, l2b, l3W, l3b, out);

    (void)in_sizes; (void)n_in; (void)out_size; (void)ws_size;
}